// Round 1
// 1083.680 us; speedup vs baseline: 1.0472x; 1.0472x over previous
//
#include <hip/hip_runtime.h>
#include <hip/hip_bf16.h>
#include <stdint.h>
#include <math.h>

#define T_TOKENS 16384
#define DIM      512
#define NEXP     8
#define HID      2048

typedef __attribute__((ext_vector_type(8))) __bf16 bf16x8;
typedef __attribute__((ext_vector_type(16))) float f32x16;

__device__ __forceinline__ f32x16 mfma32(bf16x8 a, bf16x8 b, f32x16 c) {
  return __builtin_amdgcn_mfma_f32_32x32x16_bf16(a, b, c, 0, 0, 0);
}

// ---- JAX threefry2x32, key = (0, 42) ----
__device__ __forceinline__ void threefry2x32(uint32_t k0, uint32_t k1,
                                             uint32_t x0, uint32_t x1,
                                             uint32_t* o0, uint32_t* o1) {
  uint32_t ks0 = k0, ks1 = k1, ks2 = k0 ^ k1 ^ 0x1BD11BDAu;
#define TF_ROT(v, d) (((v) << (d)) | ((v) >> (32 - (d))))
#define TF_ROUND(r) { x0 += x1; x1 = TF_ROT(x1, r); x1 ^= x0; }
  x0 += ks0; x1 += ks1;
  TF_ROUND(13) TF_ROUND(15) TF_ROUND(26) TF_ROUND(6)
  x0 += ks1; x1 += ks2 + 1u;
  TF_ROUND(17) TF_ROUND(29) TF_ROUND(16) TF_ROUND(24)
  x0 += ks2; x1 += ks0 + 2u;
  TF_ROUND(13) TF_ROUND(15) TF_ROUND(26) TF_ROUND(6)
  x0 += ks0; x1 += ks1 + 3u;
  TF_ROUND(17) TF_ROUND(29) TF_ROUND(16) TF_ROUND(24)
  x0 += ks1; x1 += ks2 + 4u;
  TF_ROUND(13) TF_ROUND(15) TF_ROUND(26) TF_ROUND(6)
  x0 += ks2; x1 += ks0 + 5u;
#undef TF_ROUND
#undef TF_ROT
  *o0 = x0; *o1 = x1;
}

// ---- XLA ErfInv32 (Giles polynomial) ----
__device__ __forceinline__ float erfinv_xla(float x) {
  float w = -log1pf(__fmul_rn(-x, x));
  float p;
  if (w < 5.0f) {
    w = __fadd_rn(w, -2.5f);
    p = 2.81022636e-08f;
    p = __fadd_rn(3.43273939e-07f, __fmul_rn(p, w));
    p = __fadd_rn(-3.5233877e-06f, __fmul_rn(p, w));
    p = __fadd_rn(-4.39150654e-06f, __fmul_rn(p, w));
    p = __fadd_rn(0.00021858087f, __fmul_rn(p, w));
    p = __fadd_rn(-0.00125372503f, __fmul_rn(p, w));
    p = __fadd_rn(-0.00417768164f, __fmul_rn(p, w));
    p = __fadd_rn(0.246640727f, __fmul_rn(p, w));
    p = __fadd_rn(1.50140941f, __fmul_rn(p, w));
  } else {
    w = __fadd_rn(sqrtf(w), -3.0f);
    p = -0.000200214257f;
    p = __fadd_rn(0.000100950558f, __fmul_rn(p, w));
    p = __fadd_rn(0.00134934322f, __fmul_rn(p, w));
    p = __fadd_rn(-0.00367342844f, __fmul_rn(p, w));
    p = __fadd_rn(0.00573950773f, __fmul_rn(p, w));
    p = __fadd_rn(-0.0076224613f, __fmul_rn(p, w));
    p = __fadd_rn(0.00943887047f, __fmul_rn(p, w));
    p = __fadd_rn(1.00167406f, __fmul_rn(p, w));
    p = __fadd_rn(2.83297682f, __fmul_rn(p, w));
  }
  return __fmul_rn(p, x);
}

__device__ __forceinline__ float jax_normal_at(uint32_t i) {
  uint32_t o0, o1;
  threefry2x32(0u, 42u, 0u, i, &o0, &o1);
  uint32_t bits = o0 ^ o1;
  float f = __fadd_rn(__uint_as_float((bits >> 9) | 0x3f800000u), -1.0f);
  const float lo = -0.99999994f;
  float u = fmaxf(lo, __fadd_rn(__fmul_rn(f, 2.0f), lo));
  return __fmul_rn(1.4142135623730951f, erfinv_xla(u));
}

// ---------------- Router: 1 wave per token, fp64 ----------------
__global__ __launch_bounds__(256) void router_kernel(
    const float* __restrict__ x, const float* __restrict__ Wr, const float* __restrict__ br,
    const float* __restrict__ Wn, const float* __restrict__ bn,
    int* __restrict__ counts, int* __restrict__ top_i, float* __restrict__ top_g) {
  int wave = threadIdx.x >> 6;
  int lane = threadIdx.x & 63;
  int t = blockIdx.x * 4 + wave;

  double accR[8], accN[8];
#pragma unroll
  for (int e = 0; e < 8; ++e) { accR[e] = 0.0; accN[e] = 0.0; }

  const float* xp = x + (size_t)t * DIM + lane * 8;
  float4 xa = *(const float4*)xp;
  float4 xb = *(const float4*)(xp + 4);
  float xv[8] = {xa.x, xa.y, xa.z, xa.w, xb.x, xb.y, xb.z, xb.w};

#pragma unroll
  for (int k = 0; k < 8; ++k) {
    int d = lane * 8 + k;
    float4 wra = *(const float4*)(Wr + (size_t)d * NEXP);
    float4 wrb = *(const float4*)(Wr + (size_t)d * NEXP + 4);
    float4 wna = *(const float4*)(Wn + (size_t)d * NEXP);
    float4 wnb = *(const float4*)(Wn + (size_t)d * NEXP + 4);
    float wr[8] = {wra.x, wra.y, wra.z, wra.w, wrb.x, wrb.y, wrb.z, wrb.w};
    float wn[8] = {wna.x, wna.y, wna.z, wna.w, wnb.x, wnb.y, wnb.z, wnb.w};
    double xk = (double)xv[k];
#pragma unroll
    for (int e = 0; e < 8; ++e) {
      accR[e] += xk * (double)wr[e];
      accN[e] += xk * (double)wn[e];
    }
  }
#pragma unroll
  for (int m = 1; m < 64; m <<= 1) {
#pragma unroll
    for (int e = 0; e < 8; ++e) {
      accR[e] += __shfl_xor(accR[e], m);
      accN[e] += __shfl_xor(accN[e], m);
    }
  }

  double noisy = -1.0e308;
  if (lane < 8) {
    int e = lane;
    double logit = accR[e] + (double)br[e];
    double nlin  = accN[e] + (double)bn[e];
    double noise = (double)jax_normal_at((uint32_t)t * 8u + (uint32_t)e);
    double sp = fmax(nlin, 0.0) + log1p(exp(-fabs(nlin)));
    noisy = logit + noise * sp;
  }
  double v[8];
#pragma unroll
  for (int e = 0; e < 8; ++e) v[e] = __shfl(noisy, e);

  if (lane == 0) {
    int i1 = 0; double v1 = v[0];
#pragma unroll
    for (int e = 1; e < 8; ++e) if (v[e] > v1) { v1 = v[e]; i1 = e; }
    int i2 = -1; double v2 = -1.0e308;
#pragma unroll
    for (int e = 0; e < 8; ++e) if (e != i1 && v[e] > v2) { v2 = v[e]; i2 = e; }
    double w2 = exp(v2 - v1);
    double s = 1.0 + w2;
    float g1 = (float)(1.0 / s), g2 = (float)(w2 / s);
    top_i[t * 2 + 0] = i1; top_g[t * 2 + 0] = g1;
    top_i[t * 2 + 1] = i2; top_g[t * 2 + 1] = g2;
    atomicAdd(&counts[i1], 1);
    atomicAdd(&counts[i2], 1);
  }
}

// offsets aligned to 32 so 32-token tiles never span experts
__global__ void scan_kernel(const int* __restrict__ counts, int* __restrict__ offsets) {
  if (threadIdx.x == 0 && blockIdx.x == 0) {
    int s = 0;
#pragma unroll
    for (int e = 0; e < NEXP; ++e) { offsets[e] = s; s += (counts[e] + 31) & ~31; }
  }
}

__global__ __launch_bounds__(256) void scatter_kernel(
    const int* __restrict__ top_i, const float* __restrict__ top_g,
    const int* __restrict__ offsets, int* __restrict__ fill,
    int* __restrict__ ltok, float* __restrict__ lgate) {
  int i = blockIdx.x * 256 + threadIdx.x;
  int e = top_i[i];
  float g = top_g[i];
  int pos = atomicAdd(&fill[e], 1);
  int dst = offsets[e] + pos;
  ltok[dst] = i >> 1;
  lgate[dst] = g;
}

// ---- transpose-pack for 32-wide MFMA B tiles:
// src [e][R][C] fp32 -> dst [e][C/32][R/8][32][8] bf16
// dst[e][nt][ko][lc][j] = src[e][ko*8+j][nt*32+lc]; coalesced via LDS transpose.
__global__ __launch_bounds__(256) void pack_bfrag32(const float* __restrict__ src,
                                                    __bf16* __restrict__ dst,
                                                    int R, int C) {
  int nct = C >> 6;
  int tilesPerE = (R >> 6) * nct;
  int e = blockIdx.x / tilesPerE;
  int rem = blockIdx.x % tilesPerE;
  int rt = rem / nct, ct = rem % nct;

  __shared__ float Ls[64][68];   // pad 68 (16B-aligned rows, bank-skewed)

  const float* s = src + (size_t)e * R * C + (size_t)(rt * 64) * C + ct * 64;
  int row = threadIdx.x >> 4;
  int col = (threadIdx.x & 15) * 4;
#pragma unroll
  for (int it = 0; it < 4; ++it) {
    float4 v = *(const float4*)(s + (size_t)(it * 16 + row) * C + col);
    *(float4*)&Ls[it * 16 + row][col] = v;
  }
  __syncthreads();

  int KO = R >> 3;
#pragma unroll
  for (int q = 0; q < 2; ++q) {
    int f = threadIdx.x + q * 256;   // (ntl*8 + kol)*32 + lc
    int lc = f & 31;
    int kol = (f >> 5) & 7;
    int ntl = f >> 8;                // 0..1 (two 32-col tiles per 64-col block)
    bf16x8 v;
#pragma unroll
    for (int j = 0; j < 8; ++j) v[j] = (__bf16)Ls[kol * 8 + j][ntl * 32 + lc];
    size_t idx = ((size_t)(e * (C >> 5) + ct * 2 + ntl) * KO + rt * 8 + kol) * 256 + lc * 8;
    *(bf16x8*)(dst + idx) = v;
  }
}

// ---------------- Fused MFMA expert FFN ------------------------------------
// 32-token tiles, XCD-pinned, mfma_f32_32x32x16 (2x arithmetic intensity per
// operand byte vs 16x16x32), hid chunks of 256 (2 n-tiles/wave -> A-frag
// reuse), explicit register-rotated B prefetch (GEMM1: 6 loads in flight,
// GEMM2: 4 in flight, first group issued before the barrier).
__global__ __launch_bounds__(256) void expert_mfma(
    const float* __restrict__ x,
    const __bf16* __restrict__ W1p, const float* __restrict__ b1,
    const __bf16* __restrict__ W2p, const float* __restrict__ b2,
    const int* __restrict__ counts, const int* __restrict__ offsets,
    const int* __restrict__ ltok, const float* __restrict__ lgate,
    float* __restrict__ out) {
  // XCD pinning: consecutive blocks round-robin across XCDs; e = blk&7 keeps
  // each expert's 4MB weight set resident in one XCD's L2.
  const int e = blockIdx.x & 7;
  const int tslot = blockIdx.x >> 3;      // 0..255
  const int cnt = counts[e];

  __shared__ __bf16 Xs[64][32][8];       // [k-octet][token][j] A-frag, 32 KB
  __shared__ __bf16 Hs[2][32][32][8];    // [buf][hid-octet][token][j], 32 KB
  __shared__ int   toks[32];
  __shared__ float gates[32];

  const int tid  = threadIdx.x;
  const int lane = tid & 63;
  const int w    = tid >> 6;
  const int hi   = lane >> 5;            // k-octet selector within K=16
  const int lm   = lane & 31;            // A row (token) / B col
  const int jj   = lane & 7;
  const int laneOff = hi * 256 + lm * 8; // element offset inside a [2][32][8] k-step

  const __bf16* w2base = W2p + (size_t)(e * 16 + w * 4) * 65536; // wave's 4 out-tiles

  for (int tile = tslot; tile * 32 < cnt; tile += 256) {
    int start = tile * 32;
    int nrow = min(32, cnt - start);
    int base = offsets[e] + start;

    __syncthreads();   // prev tile's epilogue reads of toks/gates done
    if (tid < 32) {
      int tk = 0; float g = 0.f;
      if (tid < nrow) { tk = ltok[base + tid]; g = lgate[base + tid]; }
      toks[tid] = tk; gates[tid] = g;
    }
    __syncthreads();

    // stage X tile: fp32 global -> bf16 LDS (A-frag k-octet-major)
    {
      int m = tid >> 3, seg = tid & 7;
      if (m < nrow) {
        const float* xp = x + (size_t)toks[m] * DIM + seg * 64;
#pragma unroll
        for (int s = 0; s < 8; ++s) {
          float4 f0 = *(const float4*)(xp + s * 8);
          float4 f1 = *(const float4*)(xp + s * 8 + 4);
          bf16x8 v;
          v[0] = (__bf16)f0.x; v[1] = (__bf16)f0.y; v[2] = (__bf16)f0.z; v[3] = (__bf16)f0.w;
          v[4] = (__bf16)f1.x; v[5] = (__bf16)f1.y; v[6] = (__bf16)f1.z; v[7] = (__bf16)f1.w;
          *(bf16x8*)&Xs[seg * 8 + s][m][0] = v;
        }
      } else {
        bf16x8 v;
#pragma unroll
        for (int j = 0; j < 8; ++j) v[j] = (__bf16)0.f;
#pragma unroll
        for (int s = 0; s < 8; ++s) *(bf16x8*)&Xs[seg * 8 + s][m][0] = v;
      }
    }
    __syncthreads();

    f32x16 acc2[4];
#pragma unroll
    for (int nt = 0; nt < 4; ++nt)
#pragma unroll
      for (int r = 0; r < 16; ++r) acc2[nt][r] = 0.f;

    for (int hc = 0; hc < 8; ++hc) {       // hid chunks of 256
      // ---- GEMM1: wave owns hid cols [w*64, w*64+64) of this chunk ----
      const __bf16* w1s0 = W1p + (size_t)(e * 64 + hc * 8 + w * 2) * 16384;
      const __bf16* w1s1 = w1s0 + 16384;
      f32x16 acc1[2];
#pragma unroll
      for (int q = 0; q < 2; ++q)
#pragma unroll
        for (int r = 0; r < 16; ++r) acc1[q][r] = 0.f;

      // 4-slot rotation, written 3 k-steps ahead: 6 loads in flight
      bf16x8 bb0[4], bb1[4];
#pragma unroll
      for (int s = 0; s < 3; ++s) {
        bb0[s] = *(const bf16x8*)(w1s0 + s * 512 + laneOff);
        bb1[s] = *(const bf16x8*)(w1s1 + s * 512 + laneOff);
      }
#pragma unroll
      for (int ks = 0; ks < 32; ++ks) {    // K = 512 -> 32 k-steps of 16
        if (ks < 29) {
          bb0[(ks + 3) & 3] = *(const bf16x8*)(w1s0 + (ks + 3) * 512 + laneOff);
          bb1[(ks + 3) & 3] = *(const bf16x8*)(w1s1 + (ks + 3) * 512 + laneOff);
        }
        bf16x8 av = *(const bf16x8*)&Xs[ks * 2 + hi][lm][0];
        acc1[0] = mfma32(av, bb0[ks & 3], acc1[0]);
        acc1[1] = mfma32(av, bb1[ks & 3], acc1[1]);
      }

      // ---- bias + relu -> Hs (A-frag layout for GEMM2) ----
      int buf = hc & 1;
#pragma unroll
      for (int ntl = 0; ntl < 2; ++ntl) {
        float bias = b1[e * HID + hc * 256 + w * 64 + ntl * 32 + lm];
        int ko2 = w * 8 + ntl * 4 + (lm >> 3);
#pragma unroll
        for (int r = 0; r < 16; ++r) {
          int m = (r & 3) + 8 * (r >> 2) + 4 * hi;   // 32x32 C row mapping
          Hs[buf][ko2][m][jj] = (__bf16)fmaxf(acc1[ntl][r] + bias, 0.f);
        }
      }

      // issue first W2 fragment group BEFORE the barrier: flies during sync
      bf16x8 wb[2][4];
#pragma unroll
      for (int nt = 0; nt < 4; ++nt)
        wb[0][nt] = *(const bf16x8*)(w2base + (size_t)nt * 65536 +
                                     (size_t)(hc * 32) * 256 + laneOff);

      __syncthreads();

      // ---- GEMM2: wave owns out cols [w*128, w*128+128), k = this chunk ----
#pragma unroll
      for (int ks2 = 0; ks2 < 16; ++ks2) { // 256 hid -> 16 k-steps of 16
        int cb = ks2 & 1;
        if (ks2 < 15) {
#pragma unroll
          for (int nt = 0; nt < 4; ++nt)
            wb[cb ^ 1][nt] = *(const bf16x8*)(w2base + (size_t)nt * 65536 +
                                              (size_t)(hc * 32 + (ks2 + 1) * 2) * 256 + laneOff);
        }
        bf16x8 ha = *(const bf16x8*)&Hs[buf][ks2 * 2 + hi][lm][0];
#pragma unroll
        for (int nt = 0; nt < 4; ++nt) acc2[nt] = mfma32(ha, wb[cb][nt], acc2[nt]);
      }
    }

    // epilogue: gate-weighted atomic accumulate into fp32 out
#pragma unroll
    for (int nt = 0; nt < 4; ++nt) {
      int d = w * 128 + nt * 32 + lm;
      float b2v = b2[e * DIM + d];
#pragma unroll
      for (int r = 0; r < 16; ++r) {
        int m = (r & 3) + 8 * (r >> 2) + 4 * hi;
        atomicAdd(out + (size_t)toks[m] * DIM + d, gates[m] * (acc2[nt][r] + b2v));
      }
    }
  }
}

extern "C" void kernel_launch(void* const* d_in, const int* in_sizes, int n_in,
                              void* d_out, int out_size, void* d_ws, size_t ws_size,
                              hipStream_t stream) {
  const float* x  = (const float*)d_in[0];
  const float* Wr = (const float*)d_in[1];
  const float* br = (const float*)d_in[2];
  const float* Wn = (const float*)d_in[3];
  const float* bn = (const float*)d_in[4];
  const float* W1 = (const float*)d_in[5];
  const float* b1 = (const float*)d_in[6];
  const float* W2 = (const float*)d_in[7];
  const float* b2 = (const float*)d_in[8];
  float* out = (float*)d_out;

  uint8_t* wsb = (uint8_t*)d_ws;
  int* counts   = (int*)(wsb);
  int* offsets  = (int*)(wsb + 32);
  int* fill     = (int*)(wsb + 64);
  int* top_i    = (int*)(wsb + 128);
  float* top_g  = (float*)(wsb + 131200);
  int* ltok     = (int*)(wsb + 262272);
  float* lgate  = (float*)(wsb + 394368);
  __bf16* W1p   = (__bf16*)(wsb + 532480);
  __bf16* W2p   = (__bf16*)(wsb + 532480 + 16777216);
  // total ws usage: 532480 + 2*16777216 = 34,087,680 bytes (~34.1 MB)

  hipMemsetAsync(out, 0, (size_t)out_size * sizeof(float), stream);
  hipMemsetAsync(wsb, 0, 128, stream);

  pack_bfrag32<<<2048, 256, 0, stream>>>(W1, W1p, DIM, HID);   // 8*(512/64)*(2048/64)
  pack_bfrag32<<<2048, 256, 0, stream>>>(W2, W2p, HID, DIM);   // 8*(2048/64)*(512/64)
  router_kernel<<<T_TOKENS / 4, 256, 0, stream>>>(x, Wr, br, Wn, bn, counts, top_i, top_g);
  scan_kernel<<<1, 64, 0, stream>>>(counts, offsets);
  scatter_kernel<<<(2 * T_TOKENS) / 256, 256, 0, stream>>>(top_i, top_g, offsets, fill, ltok, lgate);
  expert_mfma<<<2048, 256, 0, stream>>>(x, W1p, b1, W2p, b2, counts, offsets, ltok, lgate, out);
}